// Round 4
// baseline (577.208 us; speedup 1.0000x reference)
//
#include <hip/hip_runtime.h>
#include <hip/hip_cooperative_groups.h>

namespace cg = cooperative_groups;

#define B 16384
#define C 4
#define M 512
#define D 512
#define NBLK 1024
#define NTHR 256

struct Args {
    const float* logits;
    const float* text_embeds;
    const float* ent_memo;
    const float* text_memo;
    float* out;
    int*   blockCnt;   // 64
    uint2* candList;   // B (segmented: seg s at s*256, cnt[s] valid)
    int*   rnkB;       // B
    int*   rnkM;       // C*M
    int*   list;       // C*M
    float* part;       // 128*512
    float* S;          // C*D
};

__global__ __launch_bounds__(NTHR, 4) void fused_all(Args a)
{
    cg::grid_group grid = cg::this_grid();
    __shared__ uint2 ch[1024];       // 8 KB; aliased as float Sl[2048] in P6
    __shared__ int   wscan[8];
    __shared__ int   le[16];
    const int tid = threadIdx.x;
    const int blk = blockIdx.x;
    const int gid = blk * NTHR + tid;

    // ================= P1: softmax/entropy/argmax + segmented cand build ===
    if (gid < B) {                   // blocks 0..63 (uniform per block)
        float4 l = *reinterpret_cast<const float4*>(a.logits + (size_t)gid * 4);
        float m = l.x; int idx = 0;
        if (l.y > m) { m = l.y; idx = 1; }
        if (l.z > m) { m = l.z; idx = 2; }
        if (l.w > m) { m = l.w; idx = 3; }
        float e0 = expf(l.x - m), e1 = expf(l.y - m), e2 = expf(l.z - m), e3 = expf(l.w - m);
        float s = e0 + e1 + e2 + e3;
        float inv = 1.0f / s;
        float p0 = e0 * inv, p1 = e1 * inv, p2 = e2 * inv, p3 = e3 * inv;
        float lse = logf(s);
        float ent = -(p0 * (l.x - m - lse) + p1 * (l.y - m - lse)
                    + p2 * (l.z - m - lse) + p3 * (l.w - m - lse));
        float4 pr = { p0, p1, p2, p3 };
        *reinterpret_cast<float4*>(a.out + (size_t)B * 4 + (size_t)gid * 4) = pr;
        a.out[(size_t)B * 8 + gid] = ent;
        a.rnkB[gid] = 0;
        if (gid < C * M) a.rnkM[gid] = 0;

        const float* Ac = a.ent_memo + (idx << 9);
        bool flag = ent < Ac[M - 1];
        unsigned lo = 0;
        if (flag) {
            int l0 = 0, hi = M;              // upper_bound -> #{A <= ent}
            while (l0 < hi) { int mid = (l0 + hi) >> 1; if (Ac[mid] <= ent) l0 = mid + 1; else hi = mid; }
            lo = (unsigned)l0;
        }
        // block-level compaction (order = b ascending)
        unsigned long long mask = __ballot(flag);
        int lane = tid & 63, wv = tid >> 6;
        int prefix = __popcll(mask & ((1ull << lane) - 1ull));
        if (lane == 0) wscan[wv] = __popcll(mask);
        __syncthreads();
        int base = 0;
        for (int w = 0; w < wv; w++) base += wscan[w];
        if (flag)
            a.candList[blk * NTHR + base + prefix] =
                make_uint2(__float_as_uint(ent),
                           (lo << 16) | ((unsigned)idx << 14) | (unsigned)gid);
        if (tid == 0)
            a.blockCnt[blk] = wscan[0] + wscan[1] + wscan[2] + wscan[3];
    }
    grid.sync();

    // ================= P2: pairwise stable-rank counts (64 x 16 split) =====
    {
        int x = blk & 63, y = blk >> 6;
        int t = x * NTHR + tid;
        int c0 = a.blockCnt[4 * y + 0];
        int c1 = a.blockCnt[4 * y + 1];
        int c2 = a.blockCnt[4 * y + 2];
        int c3 = a.blockCnt[4 * y + 3];
        int o1 = c0, o2 = c0 + c1, o3 = o2 + c2, total = o3 + c3;
        for (int j = tid; j < c0; j += NTHR) ch[j]      = a.candList[(4 * y + 0) * NTHR + j];
        for (int j = tid; j < c1; j += NTHR) ch[o1 + j] = a.candList[(4 * y + 1) * NTHR + j];
        for (int j = tid; j < c2; j += NTHR) ch[o2 + j] = a.candList[(4 * y + 2) * NTHR + j];
        for (int j = tid; j < c3; j += NTHR) ch[o3 + j] = a.candList[(4 * y + 3) * NTHR + j];
        __syncthreads();

        bool candRole = tid < a.blockCnt[x];
        float e = 0.0f; int lab = -1, bidx = 0;
        if (candRole) {
            uint2 v = a.candList[t];
            e = __uint_as_float(v.x);
            lab = (int)((v.y >> 14) & 3);
            bidx = (int)(v.y & 0x3FFF);
        }
        bool memoRole = t < C * M;
        int mc = t >> 9;
        float Am = memoRole ? a.ent_memo[t] : 0.0f;

        int r = 0, rm = 0;
        for (int i = 0; i < total; i++) {
            uint2 v = ch[i];
            float e2 = __uint_as_float(v.x);
            int l2 = (int)((v.y >> 14) & 3);
            if (candRole && l2 == lab) {
                if (e2 < e || (e2 == e && (int)(v.y & 0x3FFF) < bidx)) r++;
            }
            if (memoRole && l2 == mc && e2 < Am) rm++;
        }
        if (candRole && r)  atomicAdd(&a.rnkB[t], r);
        if (memoRole && rm) atomicAdd(&a.rnkM[t], rm);
        __syncthreads();          // ch reused later
    }
    grid.sync();

    // ================= P3: rank-bijection scatter ===========================
    if (gid < C * M) {
        int rr = (gid & (M - 1)) + a.rnkM[gid];
        if (rr < M) a.list[(gid & ~(M - 1)) + rr] = gid & (M - 1);
    }
    if (gid < B) {
        if (tid < a.blockCnt[blk]) {
            uint2 v = a.candList[gid];
            int rr = (int)(v.y >> 16) + a.rnkB[gid];
            if (rr < M) a.list[(((v.y >> 14) & 3) << 9) + rr] = 0x10000 | (int)(v.y & 0x3FFF);
        }
    }
    grid.sync();

    // ================= P4: gather row-sums  |  prefetch text_embeds ========
    if (blk < 128) {
        int c = blk >> 5, seg = blk & 31;
        if (tid < 16) le[tid] = a.list[(c << 9) + seg * 16 + tid];
        __syncthreads();
        float a0 = 0.0f, a1 = 0.0f;
        for (int j = 0; j < 16; j++) {
            int e = le[j];
            const float* row = (e & 0x10000)
                ? (a.text_embeds + (size_t)(e & 0x3FFF) * D)
                : (a.text_memo + (size_t)((c << 9) | (e & (M - 1))) * D);
            a0 += row[tid];
            a1 += row[tid + 256];
        }
        a.part[(size_t)blk * D + tid] = a0;
        a.part[(size_t)blk * D + tid + 256] = a1;
    } else {
        // warm L2/L3 with text_embeds for P6 (kept live per rule #17)
        int pid = (blk - 128) * NTHR + tid;                 // 0..229375
        const float4* te = reinterpret_cast<const float4*>(a.text_embeds);
        float acc = 0.0f;
        for (int j = pid; j < (B * D / 4); j += 896 * NTHR) {
            float4 v = te[j];
            acc += v.x + v.y + v.z + v.w;
        }
        asm volatile("" :: "v"(acc));
    }
    grid.sync();

    // ================= P5: reduce partials -> S =============================
    if (gid < C * M) {
        int c = gid >> 9, d = gid & (D - 1);
        float s = 0.0f;
        for (int seg = 0; seg < 32; seg++)
            s += a.part[(size_t)((c << 5) + seg) * D + d];
        a.S[gid] = s;
    }
    grid.sync();

    // ================= P6: cosin GEMV + combines + softmaxes ================
    {
        float* Sl = reinterpret_cast<float*>(ch);           // 8 KB alias
        for (int i = tid; i < C * D; i += NTHR) Sl[i] = a.S[i];
        __syncthreads();
        int wave = tid >> 6, lane = tid & 63;
        for (int r4 = 0; r4 < 4; r4++) {
            int b = blk * 16 + wave * 4 + r4;
            float c0 = 0.0f, c1 = 0.0f, c2 = 0.0f, c3 = 0.0f;
            for (int k = 0; k < 8; k++) {
                int di = k * 64 + lane;
                float tv = a.text_embeds[(size_t)b * D + di];
                c0 += tv * Sl[di];
                c1 += tv * Sl[D + di];
                c2 += tv * Sl[2 * D + di];
                c3 += tv * Sl[3 * D + di];
            }
            for (int off = 32; off; off >>= 1) {
                c0 += __shfl_down(c0, off, 64);
                c1 += __shfl_down(c1, off, 64);
                c2 += __shfl_down(c2, off, 64);
                c3 += __shfl_down(c3, off, 64);
            }
            if (lane == 0) {
                float t0 = c0 + c2, t1 = c1 + c3;   // text_combine
                float v0 = c0 + c1, v1 = c2 + c3;   // vision_combine
                float tm = fmaxf(t0, t1);
                float te0 = expf(t0 - tm), te1 = expf(t1 - tm);
                float ts = te0 + te1;
                float mt0 = te0 / ts, mt1 = te1 / ts;
                float vm = fmaxf(v0, v1);
                float ve0 = expf(v0 - vm), ve1 = expf(v1 - vm);
                float vs = ve0 + ve1;
                float mv0 = ve0 / vs, mv1 = ve1 / vs;
                float4 o = { mt0 * mv0, mt1 * mv0, mt0 * mv1, mt1 * mv1 };
                *reinterpret_cast<float4*>(a.out + (size_t)b * 4) = o;
            }
        }
    }
}

// ---------------------------------------------------------------------------
extern "C" void kernel_launch(void* const* d_in, const int* in_sizes, int n_in,
                              void* d_out, int out_size, void* d_ws, size_t ws_size,
                              hipStream_t stream)
{
    (void)in_sizes; (void)n_in; (void)out_size; (void)ws_size;
    char* ws = (char*)d_ws;

    Args a;
    a.logits      = (const float*)d_in[0];
    a.text_embeds = (const float*)d_in[1];
    a.ent_memo    = (const float*)d_in[3];
    a.text_memo   = (const float*)d_in[4];
    a.out         = (float*)d_out;
    a.blockCnt    = (int*)(ws + 0);            // 256 B
    a.candList    = (uint2*)(ws + 256);        // 128 KB  -> 131328
    a.rnkB        = (int*)(ws + 131328);       // 64 KB   -> 196864
    a.rnkM        = (int*)(ws + 196864);       // 8 KB    -> 205056
    a.list        = (int*)(ws + 205056);       // 8 KB    -> 213248
    a.part        = (float*)(ws + 213248);     // 256 KB  -> 475392
    a.S           = (float*)(ws + 475392);     // 8 KB    -> 483584

    void* kargs[] = { &a };
    hipLaunchCooperativeKernel((const void*)fused_all, dim3(NBLK), dim3(NTHR),
                               kargs, 0, stream);
}

// Round 5
// 116.296 us; speedup vs baseline: 4.9633x; 4.9633x over previous
//
#include <hip/hip_runtime.h>

#define B 16384
#define C 4
#define M 512
#define D 512
#define NCH 16
#define NSEG 64   // B/256 candidate segments

// ---------------- K1: stats + segmented candidate build (no atomics) -------
__global__ __launch_bounds__(256) void k1_stats(
    const float* __restrict__ logits,
    const float* __restrict__ ent_memo,
    float* __restrict__ out,
    int* __restrict__ blockCnt,
    int* __restrict__ doneX,
    uint2* __restrict__ candList,
    int* __restrict__ rnkB,
    int* __restrict__ rnkM)
{
    __shared__ int wscan[4];
    const int tid = threadIdx.x, blk = blockIdx.x;
    const int gid = blk * 256 + tid;

    float4 l = *reinterpret_cast<const float4*>(logits + (size_t)gid * 4);
    float m = l.x; int idx = 0;
    if (l.y > m) { m = l.y; idx = 1; }
    if (l.z > m) { m = l.z; idx = 2; }
    if (l.w > m) { m = l.w; idx = 3; }
    float e0 = expf(l.x - m), e1 = expf(l.y - m), e2 = expf(l.z - m), e3 = expf(l.w - m);
    float s = e0 + e1 + e2 + e3;
    float inv = 1.0f / s;
    float p0 = e0 * inv, p1 = e1 * inv, p2 = e2 * inv, p3 = e3 * inv;
    float lse = logf(s);
    float ent = -(p0 * (l.x - m - lse) + p1 * (l.y - m - lse)
                + p2 * (l.z - m - lse) + p3 * (l.w - m - lse));
    float4 pr = { p0, p1, p2, p3 };
    *reinterpret_cast<float4*>(out + (size_t)B * 4 + (size_t)gid * 4) = pr;
    out[(size_t)B * 8 + gid] = ent;

    rnkB[gid] = 0;
    if (gid < C * M) rnkM[gid] = 0;
    if (gid < NSEG) doneX[gid] = 0;

    const float* Ac = ent_memo + (idx << 9);
    bool flag = ent < Ac[M - 1];
    unsigned lo = 0;
    if (flag) {
        int l0 = 0, hi = M;                  // upper_bound -> #{A <= ent}
        while (l0 < hi) { int mid = (l0 + hi) >> 1; if (Ac[mid] <= ent) l0 = mid + 1; else hi = mid; }
        lo = (unsigned)l0;
    }
    // block-level compaction (order = b ascending)
    unsigned long long mask = __ballot(flag);
    int lane = tid & 63, wv = tid >> 6;
    int prefix = __popcll(mask & ((1ull << lane) - 1ull));
    if (lane == 0) wscan[wv] = __popcll(mask);
    __syncthreads();
    int base = 0;
    for (int w = 0; w < wv; w++) base += wscan[w];
    if (flag)
        candList[blk * 256 + base + prefix] =
            make_uint2(__float_as_uint(ent),
                       (lo << 16) | ((unsigned)idx << 14) | (unsigned)gid);
    if (tid == 0)
        blockCnt[blk] = wscan[0] + wscan[1] + wscan[2] + wscan[3];
}

// ---------------- K2a: pairwise stable-rank counts + last-block scatter ----
__global__ __launch_bounds__(256) void k2a_rank_scatter(
    const float* __restrict__ ent_memo,
    const int* __restrict__ blockCnt,
    const uint2* __restrict__ candList,
    int* __restrict__ rnkB,
    int* __restrict__ rnkM,
    int* __restrict__ doneX,
    int* __restrict__ list)
{
    __shared__ uint2 ch[1024];      // 8 KB: 4 candidate segments
    __shared__ int lastFlag;
    const int x = blockIdx.x, y = blockIdx.y, tid = threadIdx.x;
    const int t = x * 256 + tid;

    int s0 = blockCnt[4 * y + 0];
    int s1 = blockCnt[4 * y + 1];
    int s2 = blockCnt[4 * y + 2];
    int s3 = blockCnt[4 * y + 3];
    int o1 = s0, o2 = s0 + s1, o3 = o2 + s2, total = o3 + s3;
    for (int j = tid; j < s0; j += 256) ch[j]      = candList[(4 * y + 0) * 256 + j];
    for (int j = tid; j < s1; j += 256) ch[o1 + j] = candList[(4 * y + 1) * 256 + j];
    for (int j = tid; j < s2; j += 256) ch[o2 + j] = candList[(4 * y + 2) * 256 + j];
    for (int j = tid; j < s3; j += 256) ch[o3 + j] = candList[(4 * y + 3) * 256 + j];
    __syncthreads();

    bool candRole = tid < blockCnt[x];
    float e = 0.0f; int lab = -1, bidx = 0; unsigned lo = 0;
    if (candRole) {
        uint2 v = candList[t];
        e = __uint_as_float(v.x);
        lab = (int)((v.y >> 14) & 3);
        bidx = (int)(v.y & 0x3FFF);
        lo = v.y >> 16;
    }
    bool memoRole = t < C * M;
    int mc = t >> 9;
    float Am = memoRole ? ent_memo[t] : 0.0f;

    int r = 0, rm = 0;
    if (candRole || memoRole) {
        for (int i = 0; i < total; i++) {
            uint2 v = ch[i];
            float e2 = __uint_as_float(v.x);
            int l2 = (int)((v.y >> 14) & 3);
            if (candRole && l2 == lab) {
                if (e2 < e || (e2 == e && (int)(v.y & 0x3FFF) < bidx)) r++;
            }
            if (memoRole && l2 == mc && e2 < Am) rm++;
        }
    }
    if (candRole && r)  atomicAdd(&rnkB[t], r);
    if (memoRole && rm) atomicAdd(&rnkM[t], rm);
    __syncthreads();                 // all block atomics issued+drained (vmcnt)
    __threadfence();
    if (tid == 0) {
        int old = atomicAdd(&doneX[x], 1);
        lastFlag = (old == NCH - 1);
    }
    __syncthreads();
    if (lastFlag) {
        __threadfence();
        if (candRole) {
            int full = atomicAdd(&rnkB[t], 0);        // coherent read
            int rr = (int)lo + full;
            if (rr < M) list[(lab << 9) + rr] = 0x10000 | bidx;
        }
        if (memoRole) {
            int fm = atomicAdd(&rnkM[t], 0);
            int rr = (t & (M - 1)) + fm;
            if (rr < M) list[(t & ~(M - 1)) + rr] = t & (M - 1);
        }
    }
}

// ---------------- K4: sum kept rows -> S (deterministic fixed tree) --------
__global__ __launch_bounds__(1024) void k4_sum(
    const int* __restrict__ list,
    const float* __restrict__ text_memo,
    const float* __restrict__ text_embeds,
    float* __restrict__ S)
{
    __shared__ int le[M];            // 2 KB
    __shared__ float red[3][256];    // 3 KB
    const int c = blockIdx.x >> 1, h = blockIdx.x & 1;
    const int tid = threadIdx.x;
    const int col = h * 256 + (tid & 255);
    const int g = tid >> 8;          // 4 row-groups of 128 serial rows

    if (tid < M) le[tid] = list[(c << 9) + tid];
    __syncthreads();

    float acc = 0.0f;
    #pragma unroll 4
    for (int j = g * 128; j < (g + 1) * 128; j++) {
        int e = le[j];
        const float* row = (e & 0x10000)
            ? (text_embeds + (size_t)(e & 0x3FFF) * D)
            : (text_memo + (size_t)((c << 9) | (e & (M - 1))) * D);
        acc += row[col];
    }
    if (g > 0) red[g - 1][tid & 255] = acc;
    __syncthreads();
    if (g == 0) {
        float total = ((acc + red[0][tid]) + red[1][tid]) + red[2][tid];
        S[(c << 9) + col] = total;
    }
}

// ---------------- K5: GEMV (S in VGPRs) + combines + softmaxes -------------
__global__ __launch_bounds__(256) void k5_cosin(
    const float* __restrict__ text_embeds,
    const float* __restrict__ S,
    float* __restrict__ out)
{
    const int tid = threadIdx.x;
    const int wave = tid >> 6, lane = tid & 63;
    const float4* S4 = reinterpret_cast<const float4*>(S);
    // per-lane S slice: label l, cols lane*8 .. lane*8+7
    float4 s00 = S4[0 * 128 + lane * 2], s01 = S4[0 * 128 + lane * 2 + 1];
    float4 s10 = S4[1 * 128 + lane * 2], s11 = S4[1 * 128 + lane * 2 + 1];
    float4 s20 = S4[2 * 128 + lane * 2], s21 = S4[2 * 128 + lane * 2 + 1];
    float4 s30 = S4[3 * 128 + lane * 2], s31 = S4[3 * 128 + lane * 2 + 1];

    for (int r4 = 0; r4 < 4; r4++) {
        int b = blockIdx.x * 16 + wave * 4 + r4;
        const float4* te4 = reinterpret_cast<const float4*>(text_embeds + (size_t)b * D);
        float4 t0 = te4[lane * 2], t1 = te4[lane * 2 + 1];
        float c0 = t0.x*s00.x + t0.y*s00.y + t0.z*s00.z + t0.w*s00.w
                 + t1.x*s01.x + t1.y*s01.y + t1.z*s01.z + t1.w*s01.w;
        float c1 = t0.x*s10.x + t0.y*s10.y + t0.z*s10.z + t0.w*s10.w
                 + t1.x*s11.x + t1.y*s11.y + t1.z*s11.z + t1.w*s11.w;
        float c2 = t0.x*s20.x + t0.y*s20.y + t0.z*s20.z + t0.w*s20.w
                 + t1.x*s21.x + t1.y*s21.y + t1.z*s21.z + t1.w*s21.w;
        float c3 = t0.x*s30.x + t0.y*s30.y + t0.z*s30.z + t0.w*s30.w
                 + t1.x*s31.x + t1.y*s31.y + t1.z*s31.z + t1.w*s31.w;
        for (int off = 32; off; off >>= 1) {
            c0 += __shfl_down(c0, off, 64);
            c1 += __shfl_down(c1, off, 64);
            c2 += __shfl_down(c2, off, 64);
            c3 += __shfl_down(c3, off, 64);
        }
        if (lane == 0) {
            float t0c = c0 + c2, t1c = c1 + c3;   // text_combine
            float v0c = c0 + c1, v1c = c2 + c3;   // vision_combine
            float tm = fmaxf(t0c, t1c);
            float te0 = expf(t0c - tm), te1 = expf(t1c - tm);
            float ts = te0 + te1;
            float mt0 = te0 / ts, mt1 = te1 / ts;
            float vm = fmaxf(v0c, v1c);
            float ve0 = expf(v0c - vm), ve1 = expf(v1c - vm);
            float vs = ve0 + ve1;
            float mv0 = ve0 / vs, mv1 = ve1 / vs;
            float4 o = { mt0 * mv0, mt1 * mv0, mt0 * mv1, mt1 * mv1 };
            *reinterpret_cast<float4*>(out + (size_t)b * 4) = o;
        }
    }
}

// ---------------------------------------------------------------------------
extern "C" void kernel_launch(void* const* d_in, const int* in_sizes, int n_in,
                              void* d_out, int out_size, void* d_ws, size_t ws_size,
                              hipStream_t stream)
{
    (void)in_sizes; (void)n_in; (void)out_size; (void)ws_size;
    const float* logits      = (const float*)d_in[0];
    const float* text_embeds = (const float*)d_in[1];
    const float* ent_memo    = (const float*)d_in[3];
    const float* text_memo   = (const float*)d_in[4];
    float* out = (float*)d_out;
    char* ws = (char*)d_ws;

    // workspace layout (bytes), all 256-aligned
    int*   blockCnt = (int*)(ws + 0);          // 256 B
    int*   doneX    = (int*)(ws + 256);        // 256 B   -> 512
    uint2* candList = (uint2*)(ws + 512);      // 128 KB  -> 131584
    int*   rnkB     = (int*)(ws + 131584);     // 64 KB   -> 197120
    int*   rnkM     = (int*)(ws + 197120);     // 8 KB    -> 205312
    int*   list     = (int*)(ws + 205312);     // 8 KB    -> 213504
    float* S        = (float*)(ws + 213504);   // 8 KB    -> 221696

    k1_stats<<<NSEG, 256, 0, stream>>>(logits, ent_memo, out, blockCnt, doneX,
                                       candList, rnkB, rnkM);
    k2a_rank_scatter<<<dim3(NSEG, NCH), 256, 0, stream>>>(ent_memo, blockCnt,
                                                          candList, rnkB, rnkM,
                                                          doneX, list);
    k4_sum<<<8, 1024, 0, stream>>>(list, text_memo, text_embeds, S);
    k5_cosin<<<B / 16, 256, 0, stream>>>(text_embeds, S, out);
}

// Round 6
// 73.536 us; speedup vs baseline: 7.8493x; 1.5815x over previous
//
#include <hip/hip_runtime.h>

#define B 16384
#define C 4
#define M 512
#define D 512
#define NCH 16
#define NSEG 64   // B/256 candidate segments

// ---------------- K1: stats + segmented candidate build (no atomics) -------
__global__ __launch_bounds__(256) void k1_stats(
    const float* __restrict__ logits,
    const float* __restrict__ ent_memo,
    float* __restrict__ out,
    int* __restrict__ blockCnt,
    uint2* __restrict__ candList,
    int* __restrict__ rnkB,
    int* __restrict__ rnkM)
{
    __shared__ int wscan[4];
    const int tid = threadIdx.x, blk = blockIdx.x;
    const int gid = blk * 256 + tid;

    float4 l = *reinterpret_cast<const float4*>(logits + (size_t)gid * 4);
    float m = l.x; int idx = 0;
    if (l.y > m) { m = l.y; idx = 1; }
    if (l.z > m) { m = l.z; idx = 2; }
    if (l.w > m) { m = l.w; idx = 3; }
    float e0 = expf(l.x - m), e1 = expf(l.y - m), e2 = expf(l.z - m), e3 = expf(l.w - m);
    float s = e0 + e1 + e2 + e3;
    float inv = 1.0f / s;
    float p0 = e0 * inv, p1 = e1 * inv, p2 = e2 * inv, p3 = e3 * inv;
    float lse = logf(s);
    float ent = -(p0 * (l.x - m - lse) + p1 * (l.y - m - lse)
                + p2 * (l.z - m - lse) + p3 * (l.w - m - lse));
    float4 pr = { p0, p1, p2, p3 };
    *reinterpret_cast<float4*>(out + (size_t)B * 4 + (size_t)gid * 4) = pr;
    out[(size_t)B * 8 + gid] = ent;

    rnkB[gid] = 0;
    if (gid < C * M) rnkM[gid] = 0;

    const float* Ac = ent_memo + (idx << 9);
    bool flag = ent < Ac[M - 1];
    unsigned lo = 0;
    if (flag) {
        int l0 = 0, hi = M;                  // upper_bound -> #{A <= ent}
        while (l0 < hi) { int mid = (l0 + hi) >> 1; if (Ac[mid] <= ent) l0 = mid + 1; else hi = mid; }
        lo = (unsigned)l0;
    }
    // block-level compaction (order = b ascending within segment)
    unsigned long long mask = __ballot(flag);
    int lane = tid & 63, wv = tid >> 6;
    int prefix = __popcll(mask & ((1ull << lane) - 1ull));
    if (lane == 0) wscan[wv] = __popcll(mask);
    __syncthreads();
    int base = 0;
    for (int w = 0; w < wv; w++) base += wscan[w];
    if (flag)
        candList[blk * 256 + base + prefix] =
            make_uint2(__float_as_uint(ent),
                       (lo << 16) | ((unsigned)idx << 14) | (unsigned)gid);
    if (tid == 0)
        blockCnt[blk] = wscan[0] + wscan[1] + wscan[2] + wscan[3];
}

// ---------------- K2a: pairwise stable-rank partial counts (no tail) -------
// grid (NSEG+8, NCH): x<NSEG -> candidate-role block x; x>=NSEG -> memo rows.
__global__ __launch_bounds__(256) void k2a_count(
    const float* __restrict__ ent_memo,
    const int* __restrict__ blockCnt,
    const uint2* __restrict__ candList,
    int* __restrict__ rnkB,
    int* __restrict__ rnkM)
{
    __shared__ uint2 ch[1024];      // 4 candidate segments of this y-chunk
    const int x = blockIdx.x, y = blockIdx.y, tid = threadIdx.x;

    int s0 = blockCnt[4 * y + 0];
    int s1 = blockCnt[4 * y + 1];
    int s2 = blockCnt[4 * y + 2];
    int s3 = blockCnt[4 * y + 3];
    int o1 = s0, o2 = s0 + s1, o3 = o2 + s2, total = o3 + s3;
    for (int j = tid; j < s0; j += 256) ch[j]      = candList[(4 * y + 0) * 256 + j];
    for (int j = tid; j < s1; j += 256) ch[o1 + j] = candList[(4 * y + 1) * 256 + j];
    for (int j = tid; j < s2; j += 256) ch[o2 + j] = candList[(4 * y + 2) * 256 + j];
    for (int j = tid; j < s3; j += 256) ch[o3 + j] = candList[(4 * y + 3) * 256 + j];
    __syncthreads();

    if (x < NSEG) {
        // candidate role: rank among same-label candidates of this chunk
        if (tid < blockCnt[x]) {
            uint2 v = candList[x * 256 + tid];
            float e = __uint_as_float(v.x);
            int lab = (int)((v.y >> 14) & 3);
            int bidx = (int)(v.y & 0x3FFF);
            int r = 0;
            for (int i = 0; i < total; i++) {
                uint2 w = ch[i];
                float e2 = __uint_as_float(w.x);
                if ((int)((w.y >> 14) & 3) == lab &&
                    (e2 < e || (e2 == e && (int)(w.y & 0x3FFF) < bidx))) r++;
            }
            if (r) atomicAdd(&rnkB[x * 256 + tid], r);
        }
    } else {
        // memo role: count same-label candidates strictly below A[t]
        int t = (x - NSEG) * 256 + tid;       // [0, C*M)
        float Am = ent_memo[t];
        int mc = t >> 9;
        int rm = 0;
        for (int i = 0; i < total; i++) {
            uint2 w = ch[i];
            if ((int)((w.y >> 14) & 3) == mc && __uint_as_float(w.x) < Am) rm++;
        }
        if (rm) atomicAdd(&rnkM[t], rm);
    }
}

// ---------------- K4: rebuild kept-list in LDS + sum rows -> S -------------
// 8 blocks (c,h) x 1024 threads. Rank bijection: every rank in [0,M) is hit
// exactly once, so le[] is fully written. Deterministic fixed-tree reduce.
__global__ __launch_bounds__(1024) void k4_sum(
    const int* __restrict__ blockCnt,
    const uint2* __restrict__ candList,
    const int* __restrict__ rnkB,
    const int* __restrict__ rnkM,
    const float* __restrict__ text_memo,
    const float* __restrict__ text_embeds,
    float* __restrict__ S)
{
    __shared__ int le[M];            // 2 KB
    __shared__ float red[3][256];    // 3 KB
    const int c = blockIdx.x >> 1, h = blockIdx.x & 1;
    const int tid = threadIdx.x;

    // memo rows: rank = i + rnkM[i]
    if (tid < M) {
        int r = tid + rnkM[(c << 9) + tid];
        if (r < M) le[r] = tid;
    }
    // batch candidates: rank = lo + rnkB[slot]
    for (int slot = tid; slot < B; slot += 1024) {
        int seg = slot >> 8, j = slot & 255;
        if (j < blockCnt[seg]) {
            uint2 v = candList[slot];
            if ((int)((v.y >> 14) & 3) == c) {
                int r = (int)(v.y >> 16) + rnkB[slot];
                if (r < M) le[r] = 0x10000 | (int)(v.y & 0x3FFF);
            }
        }
    }
    __syncthreads();

    const int col = h * 256 + (tid & 255);
    const int g = tid >> 8;          // 4 row-groups of 128 serial rows
    float acc = 0.0f;
    #pragma unroll 4
    for (int j = g * 128; j < (g + 1) * 128; j++) {
        int e = le[j];
        const float* row = (e & 0x10000)
            ? (text_embeds + (size_t)(e & 0x3FFF) * D)
            : (text_memo + (size_t)((c << 9) | (e & (M - 1))) * D);
        acc += row[col];
    }
    if (g > 0) red[g - 1][tid & 255] = acc;
    __syncthreads();
    if (g == 0) {
        float total = ((acc + red[0][tid]) + red[1][tid]) + red[2][tid];
        S[(c << 9) + col] = total;
    }
}

// ---------------- K5: GEMV (S in VGPRs) + combines + softmaxes -------------
__global__ __launch_bounds__(256) void k5_cosin(
    const float* __restrict__ text_embeds,
    const float* __restrict__ S,
    float* __restrict__ out)
{
    const int tid = threadIdx.x;
    const int wave = tid >> 6, lane = tid & 63;
    const float4* S4 = reinterpret_cast<const float4*>(S);
    float4 s00 = S4[0 * 128 + lane * 2], s01 = S4[0 * 128 + lane * 2 + 1];
    float4 s10 = S4[1 * 128 + lane * 2], s11 = S4[1 * 128 + lane * 2 + 1];
    float4 s20 = S4[2 * 128 + lane * 2], s21 = S4[2 * 128 + lane * 2 + 1];
    float4 s30 = S4[3 * 128 + lane * 2], s31 = S4[3 * 128 + lane * 2 + 1];

    for (int r4 = 0; r4 < 4; r4++) {
        int b = blockIdx.x * 16 + wave * 4 + r4;
        const float4* te4 = reinterpret_cast<const float4*>(text_embeds + (size_t)b * D);
        float4 t0 = te4[lane * 2], t1 = te4[lane * 2 + 1];
        float c0 = t0.x*s00.x + t0.y*s00.y + t0.z*s00.z + t0.w*s00.w
                 + t1.x*s01.x + t1.y*s01.y + t1.z*s01.z + t1.w*s01.w;
        float c1 = t0.x*s10.x + t0.y*s10.y + t0.z*s10.z + t0.w*s10.w
                 + t1.x*s11.x + t1.y*s11.y + t1.z*s11.z + t1.w*s11.w;
        float c2 = t0.x*s20.x + t0.y*s20.y + t0.z*s20.z + t0.w*s20.w
                 + t1.x*s21.x + t1.y*s21.y + t1.z*s21.z + t1.w*s21.w;
        float c3 = t0.x*s30.x + t0.y*s30.y + t0.z*s30.z + t0.w*s30.w
                 + t1.x*s31.x + t1.y*s31.y + t1.z*s31.z + t1.w*s31.w;
        for (int off = 32; off; off >>= 1) {
            c0 += __shfl_down(c0, off, 64);
            c1 += __shfl_down(c1, off, 64);
            c2 += __shfl_down(c2, off, 64);
            c3 += __shfl_down(c3, off, 64);
        }
        if (lane == 0) {
            float t0c = c0 + c2, t1c = c1 + c3;   // text_combine
            float v0c = c0 + c1, v1c = c2 + c3;   // vision_combine
            float tm = fmaxf(t0c, t1c);
            float te0 = expf(t0c - tm), te1 = expf(t1c - tm);
            float ts = te0 + te1;
            float mt0 = te0 / ts, mt1 = te1 / ts;
            float vm = fmaxf(v0c, v1c);
            float ve0 = expf(v0c - vm), ve1 = expf(v1c - vm);
            float vs = ve0 + ve1;
            float mv0 = ve0 / vs, mv1 = ve1 / vs;
            float4 o = { mt0 * mv0, mt1 * mv0, mt0 * mv1, mt1 * mv1 };
            *reinterpret_cast<float4*>(out + (size_t)b * 4) = o;
        }
    }
}

// ---------------------------------------------------------------------------
extern "C" void kernel_launch(void* const* d_in, const int* in_sizes, int n_in,
                              void* d_out, int out_size, void* d_ws, size_t ws_size,
                              hipStream_t stream)
{
    (void)in_sizes; (void)n_in; (void)out_size; (void)ws_size;
    const float* logits      = (const float*)d_in[0];
    const float* text_embeds = (const float*)d_in[1];
    const float* ent_memo    = (const float*)d_in[3];
    const float* text_memo   = (const float*)d_in[4];
    float* out = (float*)d_out;
    char* ws = (char*)d_ws;

    // workspace layout (bytes), 256-aligned
    int*   blockCnt = (int*)(ws + 0);          // 256 B
    uint2* candList = (uint2*)(ws + 256);      // 128 KB  -> 131328
    int*   rnkB     = (int*)(ws + 131328);     // 64 KB   -> 196864
    int*   rnkM     = (int*)(ws + 196864);     // 8 KB    -> 205056
    float* S        = (float*)(ws + 205056);   // 8 KB    -> 213248

    k1_stats<<<NSEG, 256, 0, stream>>>(logits, ent_memo, out, blockCnt,
                                       candList, rnkB, rnkM);
    k2a_count<<<dim3(NSEG + 8, NCH), 256, 0, stream>>>(ent_memo, blockCnt,
                                                       candList, rnkB, rnkM);
    k4_sum<<<8, 1024, 0, stream>>>(blockCnt, candList, rnkB, rnkM,
                                   text_memo, text_embeds, S);
    k5_cosin<<<B / 16, 256, 0, stream>>>(text_embeds, S, out);
}